// Round 6
// baseline (592.036 us; speedup 1.0000x reference)
//
#include <hip/hip_runtime.h>
#include <stdint.h>

// GNNAutoEncoder: 2x SAGEConv(mean) + edge MLP decoder.
// N=100000 nodes, E=1600000 edges, D=256, HIDDEN=256, OUT=128.
static constexpr int NN = 100000;
static constexpr int NE = 1600000;
static constexpr int NB_SCAN = (NN + 255) / 256;  // 391
static constexpr int NB_CVTX = NN * 256 / 4 / 256;  // 25000
static constexpr int NB_HIST = NE / 256;            // 6250
static constexpr int NB_CVTW = 897;

typedef __bf16 bf16;
typedef __bf16 bf16x4 __attribute__((ext_vector_type(4)));
typedef __bf16 bf16x8 __attribute__((ext_vector_type(8)));
typedef float floatx4 __attribute__((ext_vector_type(4)));

// async global->LDS, 16B per lane. LDS dest is wave-uniform base + lane*16.
__device__ __forceinline__ void async16(const void* g, void* l) {
  __builtin_amdgcn_global_load_lds(
      (const __attribute__((address_space(1))) void*)g,
      (__attribute__((address_space(3))) void*)l, 16, 0, 0);
}

// pack 4 floats -> 4 OCP e4m3 bytes
__device__ __forceinline__ uint32_t pk4_fp8(float a, float b, float c, float d) {
  uint32_t v = 0;
  v = (uint32_t)__builtin_amdgcn_cvt_pk_fp8_f32(a, b, (int)v, false);
  v = (uint32_t)__builtin_amdgcn_cvt_pk_fp8_f32(c, d, (int)v, true);
  return v;
}

// accumulate 8 fp8 (uint2) into float[8]
__device__ __forceinline__ void acc_fp8x8(float* a, uint2 v) {
  a[0] += __builtin_amdgcn_cvt_f32_fp8(v.x, 0);
  a[1] += __builtin_amdgcn_cvt_f32_fp8(v.x, 1);
  a[2] += __builtin_amdgcn_cvt_f32_fp8(v.x, 2);
  a[3] += __builtin_amdgcn_cvt_f32_fp8(v.x, 3);
  a[4] += __builtin_amdgcn_cvt_f32_fp8(v.y, 0);
  a[5] += __builtin_amdgcn_cvt_f32_fp8(v.y, 1);
  a[6] += __builtin_amdgcn_cvt_f32_fp8(v.y, 2);
  a[7] += __builtin_amdgcn_cvt_f32_fp8(v.y, 3);
}

// clamp a gathered index into [0, NN) -- defensive: turns any CSR corruption
// into a wrong answer (diagnosable) instead of a wild-pointer page fault.
__device__ __forceinline__ int clampN(int c) {
  return ((unsigned)c < (unsigned)NN) ? c : 0;
}

// ---------------- fused: x->bf16+fp8 convert | dst histogram + rank ----------------
// XCD-LOCAL histograms: 8 copies of cnt indexed by HW_REG_XCC_ID, updated with
// workgroup-scope atomics executing in the local TCC (XCD-coherent; each XCD
// touches only its own slice). Atomic return = XCD-local rank, (xcd<<12)|rank.
__global__ void k_cvtx_hist(const float* __restrict__ x, bf16* __restrict__ xb,
                            uint32_t* __restrict__ xq,
                            const int* __restrict__ dst, int* __restrict__ cnt8,
                            uint16_t* __restrict__ rank) {
  int b = blockIdx.x;  // 31250 = 5 * 6250 blocks
  int m = b % 5;
  if (m < 4) {
    int cb = (b / 5) * 4 + m;  // 0..24999
    int t = cb * 256 + threadIdx.x;  // 4 elems / thread
    const float4 v = ((const float4*)x)[t];
    bf16x4 o;
    o.x = (bf16)v.x; o.y = (bf16)v.y; o.z = (bf16)v.z; o.w = (bf16)v.w;
    ((bf16x4*)xb)[t] = o;
    xq[t] = pk4_fp8(v.x, v.y, v.z, v.w);
  } else {
    int hb = b / 5;  // 0..6249
    int e = hb * 256 + threadIdx.x;
    uint32_t xcd;
    asm("s_getreg_b32 %0, hwreg(HW_REG_XCC_ID)" : "=s"(xcd));
    xcd &= 7u;
    int d = dst[e];
    int old = __hip_atomic_fetch_add(&cnt8[(size_t)xcd * NN + d], 1,
                                     __ATOMIC_RELAXED, __HIP_MEMORY_SCOPE_WORKGROUP);
    rank[e] = (uint16_t)((xcd << 12) | ((uint32_t)old & 0xFFFu));
  }
}

// ---------------- fused: weight packs | scan partials ----------------
__global__ void k_cvtw_scanpart(
    const float* __restrict__ W1l, const float* __restrict__ W1r,
    const float* __restrict__ W2l, const float* __restrict__ W2r,
    const float* __restrict__ Wd1, const float* __restrict__ bd1,
    bf16* __restrict__ B1, bf16* __restrict__ B2,
    bf16* __restrict__ Bd, float* __restrict__ biasPQ,
    const int* __restrict__ cnt8, int* __restrict__ part, int N) {
  int b = blockIdx.x;
  if (b < NB_CVTW) {
    int g = b * 256 + threadIdx.x;  // 229632 total
    if (g < 131072) {
      int o = g >> 9, k = g & 511;
      float v = (k < 256) ? W1l[o * 256 + k] : W1r[o * 256 + k - 256];
      B1[g] = (bf16)v;
    } else if (g < 131072 + 65536) {
      int t = g - 131072;
      int o = t >> 8, k = t & 255;
      float v = (o < 128) ? W2l[o * 256 + k] : W2r[(o - 128) * 256 + k];
      B2[t] = (bf16)v;
    } else if (g < 131072 + 65536 + 32768) {
      int t = g - 196608;
      int o = t >> 7, k = t & 127;
      float v = (o < 128) ? Wd1[o * 256 + k] : Wd1[(o - 128) * 256 + 128 + k];
      Bd[t] = (bf16)v;
    } else if (g < 131072 + 65536 + 32768 + 256) {
      int t = g - 229376;
      biasPQ[t] = (t < 128) ? bd1[t] : 0.0f;
    }
  } else {
    __shared__ int sh[256];
    int bb = b - NB_CVTW;
    int t = threadIdx.x;
    int i = bb * 256 + t;
    int tot = 0;
    if (i < N) {
#pragma unroll
      for (int xx = 0; xx < 8; ++xx) tot += cnt8[(size_t)xx * NN + i];
    }
    sh[t] = tot;
    __syncthreads();
    for (int off = 128; off > 0; off >>= 1) {
      if (t < off) sh[t] += sh[t + off];
      __syncthreads();
    }
    if (t == 0) part[bb] = sh[0];
  }
}

__global__ __launch_bounds__(512) void k_scan_mid(int* __restrict__ part, int NB) {
  __shared__ int sh[512];
  int t = threadIdx.x;
  int v = (t < NB) ? part[t] : 0;
  sh[t] = v;
  __syncthreads();
  for (int off = 1; off < 512; off <<= 1) {
    int u = (t >= off) ? sh[t - off] : 0;
    __syncthreads();
    sh[t] += u;
    __syncthreads();
  }
  if (t < NB) part[t] = sh[t] - v;  // exclusive
}

// exclusive prefix over per-node totals; converts cnt8 IN PLACE into
// per-(xcd,node) CSR bases: rptr8[x][n] = rowptr[n] + sum_{y<x} cnt8[y][n].
__global__ void k_scan_fin(int* __restrict__ cnt8, const int* __restrict__ part,
                           int* __restrict__ rowptr, int N, int E) {
  __shared__ int sh[256];
  int t = threadIdx.x;
  int i = blockIdx.x * 256 + t;
  int c[8];
  int v = 0;
  if (i < N) {
#pragma unroll
    for (int xx = 0; xx < 8; ++xx) { c[xx] = cnt8[(size_t)xx * NN + i]; v += c[xx]; }
  } else {
#pragma unroll
    for (int xx = 0; xx < 8; ++xx) c[xx] = 0;
  }
  sh[t] = v;
  __syncthreads();
  for (int off = 1; off < 256; off <<= 1) {
    int u = (t >= off) ? sh[t - off] : 0;
    __syncthreads();
    sh[t] += u;
    __syncthreads();
  }
  if (i < N) {
    int base = part[blockIdx.x] + sh[t] - v;  // exclusive prefix
    rowptr[i] = base;
#pragma unroll
    for (int xx = 0; xx < 8; ++xx) { cnt8[(size_t)xx * NN + i] = base; base += c[xx]; }
  }
  if (i == 0) rowptr[N] = E;
}

// atomic-free CSR fill: pos = rptr8[xcd][dst] + local_rank (both from hist).
__global__ void k_fill(const int* __restrict__ src, const int* __restrict__ dst,
                       const int* __restrict__ rptr8,
                       const uint16_t* __restrict__ rank,
                       int* __restrict__ csr, int E) {
  int e = blockIdx.x * 256 + threadIdx.x;
  if (e < E) {
    int d = dst[e];
    uint32_t rv = rank[e];
    int pos = rptr8[(size_t)(rv >> 12) * NN + d] + (int)(rv & 0xFFFu);
    if ((unsigned)pos >= (unsigned)E) pos = 0;  // defensive
    csr[pos] = src[e];
  }
}

// ---------------- layer-1 mean aggregation (fp8 gather, 256 cols) ----------------
__global__ void k_agg(const uint8_t* __restrict__ xq, const int* __restrict__ rowptr,
                      const int* __restrict__ csr, bf16* __restrict__ mean) {
  int wave = threadIdx.x >> 6, lane = threadIdx.x & 63;
  int n = blockIdx.x * 4 + wave;
  int s = rowptr[n], e = rowptr[n + 1];
  int half = lane >> 5, l32 = lane & 31;
  float a[8] = {};
  const uint8_t* base = xq + l32 * 8;
  int i = s + half;
  for (; i + 6 < e; i += 8) {
    int c0 = clampN(csr[i]), c1 = clampN(csr[i + 2]);
    int c2 = clampN(csr[i + 4]), c3 = clampN(csr[i + 6]);
    uint2 v0 = *(const uint2*)(base + (size_t)c0 * 256);
    uint2 v1 = *(const uint2*)(base + (size_t)c1 * 256);
    uint2 v2 = *(const uint2*)(base + (size_t)c2 * 256);
    uint2 v3 = *(const uint2*)(base + (size_t)c3 * 256);
    acc_fp8x8(a, v0); acc_fp8x8(a, v1); acc_fp8x8(a, v2); acc_fp8x8(a, v3);
  }
  for (; i < e; i += 2) {
    uint2 v = *(const uint2*)(base + (size_t)clampN(csr[i]) * 256);
    acc_fp8x8(a, v);
  }
  int deg = e - s;
  float sc = 1.0f / (float)(deg > 0 ? deg : 1);
  bf16x8 o;
#pragma unroll
  for (int j = 0; j < 8; ++j) {
    float t = a[j] + __shfl_xor(a[j], 32);
    o[j] = (bf16)(t * sc);
  }
  if (half == 0)
    *(bf16x8*)(mean + (size_t)n * 256 + l32 * 8) = o;
}

// ---------------- layer-2 aggregate+combine (fp8 hl gather, 128 cols) ----------------
__global__ void k_agg2z(const uint8_t* __restrict__ hq, const bf16* __restrict__ hr,
                        const int* __restrict__ rowptr, const int* __restrict__ csr,
                        const float* __restrict__ b2l, bf16* __restrict__ zf) {
  int wave = threadIdx.x >> 6, lane = threadIdx.x & 63;
  int n = blockIdx.x * 4 + wave;
  int s = rowptr[n], e = rowptr[n + 1];
  int sub = lane >> 4, l16 = lane & 15;
  float a[8] = {};
  const uint8_t* base = hq + l16 * 8;
  int i = s + sub;
  for (; i + 4 < e; i += 8) {
    int c0 = clampN(csr[i]), c1 = clampN(csr[i + 4]);
    uint2 v0 = *(const uint2*)(base + (size_t)c0 * 128);
    uint2 v1 = *(const uint2*)(base + (size_t)c1 * 128);
    acc_fp8x8(a, v0); acc_fp8x8(a, v1);
  }
  for (; i < e; i += 4) {
    uint2 v = *(const uint2*)(base + (size_t)clampN(csr[i]) * 128);
    acc_fp8x8(a, v);
  }
  int deg = e - s;
  float sc = 1.0f / (float)(deg > 0 ? deg : 1);
  bf16x8 hv = *(const bf16x8*)(hr + (size_t)n * 128 + l16 * 8);
  const float4* b4 = (const float4*)(b2l + l16 * 8);
  float4 ba = b4[0], bb = b4[1];
  float bl[8] = {ba.x, ba.y, ba.z, ba.w, bb.x, bb.y, bb.z, bb.w};
  bf16x8 o;
#pragma unroll
  for (int j = 0; j < 8; ++j) {
    float t = a[j];
    t += __shfl_xor(t, 16);
    t += __shfl_xor(t, 32);
    o[j] = (bf16)(t * sc + (float)hv[j] + bl[j]);
  }
  if (sub == 0)
    *(bf16x8*)(zf + (size_t)n * 128 + l16 * 8) = o;
}

// ---------------- FUSED conv1 GEMM + conv2 transform (128-row, dbuf+counted vmcnt) ----
// Phase 1 (steps 0..7):  h = relu([mean|x] @ B1^T + b1l), acc in regs -> Hs (LDS).
// Phase 2 (steps 8..11): [hq|hr] = h @ B2^T, A read from Hs; h never touches HBM.
// Pipelined staging: stage(s+1) issued BEFORE computing step s; waits are
// counted (vmcnt(6)/vmcnt(4) = loads of stage s+1 left in flight), never 0 in
// the main loop -- removes the per-step full drain that capped r4/r5 at ~85us.
// 8 waves (512 thr), wave tile 64x64. LDS = Hs 64KB + 2xAs 32KB + 2xBs 64KB
// = 160KB exactly (1 block/CU; drains are pipelined away so this is fine --
// same budget AITER's 160KB-LDS kernels use on gfx950).
__global__ __launch_bounds__(512) void k_fused12(
    const bf16* __restrict__ A1, const bf16* __restrict__ A2,
    const bf16* __restrict__ B1, const float* __restrict__ b1l,
    const bf16* __restrict__ B2, uint8_t* __restrict__ hq,
    bf16* __restrict__ hr, int Nrows) {
  __shared__ bf16 Hs[128 * 256];     // 64KB; chunk c of row stored at c^(row&7)
  __shared__ bf16 As[2][128 * 64];   // 2 x 16KB
  __shared__ bf16 Bs[2][256 * 64];   // 2 x 32KB
  const int tid = threadIdx.x, wave = tid >> 6, lane = tid & 63;
  const int quad = lane >> 4, l16 = lane & 15;
  const int rowBase = blockIdx.x * 128;
  const int wr = (wave >> 2) * 64;  // 0,64
  const int wc = (wave & 3) * 64;   // 0,64,128,192
  floatx4 acc[4][4] = {};

  // stage helpers: 2 A-loads + 4 B1-loads (phase1) or 4 B2-loads (phase2) per thread
  auto stageA = [&](int kc, bf16* dst) {
    const bf16* Asrc = (kc < 4) ? A1 : A2;
    const int kb = (kc & 3) * 64;
#pragma unroll
    for (int i = 0; i < 2; ++i) {
      int u = wave * 128 + i * 64 + lane;
      int row = u >> 3, seg = u & 7;
      int sg = seg ^ (row & 7);
      int node = rowBase + row;
      if (node >= Nrows) node = Nrows - 1;
      async16(Asrc + (size_t)node * 256 + kb + sg * 8, dst + (wave * 128 + i * 64) * 8);
    }
  };
  auto stageB1 = [&](int kc, bf16* dst) {
#pragma unroll
    for (int i = 0; i < 4; ++i) {
      int u = wave * 256 + i * 64 + lane;
      int row = u >> 3, seg = u & 7;
      int sg = seg ^ (row & 7);
      async16(B1 + (size_t)row * 512 + kc * 64 + sg * 8, dst + (wave * 256 + i * 64) * 8);
    }
  };
  auto stageB2 = [&](int kc, bf16* dst) {
#pragma unroll
    for (int i = 0; i < 4; ++i) {
      int u = wave * 256 + i * 64 + lane;
      int row = u >> 3, seg = u & 7;
      int sg = seg ^ (row & 7);
      async16(B2 + (size_t)row * 256 + kc * 64 + sg * 8, dst + (wave * 256 + i * 64) * 8);
    }
  };

  // prologue: stage step 0
  stageA(0, As[0]);
  stageB1(0, Bs[0]);

  for (int s = 0; s < 12; ++s) {
    const int nb = s + 1;
    // issue next step's loads into the other buffer (stays in flight across barrier)
    if (nb < 8) {
      stageA(nb, As[nb & 1]);
      stageB1(nb, Bs[nb & 1]);
      asm volatile("s_waitcnt vmcnt(6)" ::: "memory");  // step-s loads landed
    } else if (nb < 12) {
      stageB2(nb - 8, Bs[nb & 1]);
      asm volatile("s_waitcnt vmcnt(4)" ::: "memory");
    } else {
      asm volatile("s_waitcnt vmcnt(0)" ::: "memory");
    }
    __builtin_amdgcn_sched_barrier(0);
    __builtin_amdgcn_s_barrier();  // all waves' step-s stage complete

    if (s < 8) {
      // phase 1 compute from As[s&1], Bs[s&1]
      const bf16* asb = As[s & 1];
      const bf16* bsb = Bs[s & 1];
      for (int ks = 0; ks < 2; ++ks) {
        bf16x8 af[4], bq[4];
        const int sw = (ks * 4 + quad) ^ (l16 & 7);
        for (int mt = 0; mt < 4; ++mt)
          af[mt] = *(const bf16x8*)&asb[(wr + mt * 16 + l16) * 64 + sw * 8];
        for (int nt = 0; nt < 4; ++nt)
          bq[nt] = *(const bf16x8*)&bsb[(wc + nt * 16 + l16) * 64 + sw * 8];
        for (int mt = 0; mt < 4; ++mt)
          for (int nt = 0; nt < 4; ++nt)
            acc[mt][nt] = __builtin_amdgcn_mfma_f32_16x16x32_bf16(af[mt], bq[nt], acc[mt][nt], 0, 0, 0);
      }
      if (s == 7) {
        // epilogue 1: bias + relu -> Hs; zero acc for phase 2
        float bv1[4];
        for (int nt = 0; nt < 4; ++nt) bv1[nt] = b1l[wc + nt * 16 + l16];
        for (int mt = 0; mt < 4; ++mt)
          for (int nt = 0; nt < 4; ++nt) {
            int col = wc + nt * 16 + l16;
            int c = col >> 3;
            for (int r = 0; r < 4; ++r) {
              int row = wr + mt * 16 + quad * 4 + r;
              float v = fmaxf(acc[mt][nt][r] + bv1[nt], 0.0f);
              Hs[row * 256 + (c ^ (row & 7)) * 8 + (col & 7)] = (bf16)v;
              acc[mt][nt][r] = 0.0f;
            }
          }
      }
    } else {
      // phase 2 compute: A from Hs, B from Bs[s&1]
      const bf16* bsb = Bs[s & 1];
      const int kc = s - 8;
      for (int ks = 0; ks < 2; ++ks) {
        bf16x8 af[4], bq[4];
        const int swb = (ks * 4 + quad) ^ (l16 & 7);
        const int ck = kc * 8 + ks * 4 + quad;  // global h chunk 0..31
        for (int mt = 0; mt < 4; ++mt) {
          int row = wr + mt * 16 + l16;
          af[mt] = *(const bf16x8*)&Hs[row * 256 + (ck ^ (row & 7)) * 8];
        }
        for (int nt = 0; nt < 4; ++nt)
          bq[nt] = *(const bf16x8*)&bsb[(wc + nt * 16 + l16) * 64 + swb * 8];
        for (int mt = 0; mt < 4; ++mt)
          for (int nt = 0; nt < 4; ++nt)
            acc[mt][nt] = __builtin_amdgcn_mfma_f32_16x16x32_bf16(af[mt], bq[nt], acc[mt][nt], 0, 0, 0);
      }
    }
    __builtin_amdgcn_s_barrier();  // readers done before buffer re-staged
  }

  // epilogue 2: oc<128 -> hq fp8, oc>=128 -> hr bf16 (no bias)
  for (int mt = 0; mt < 4; ++mt)
    for (int nt = 0; nt < 4; ++nt) {
      int oc = wc + nt * 16 + l16;
      for (int r = 0; r < 4; ++r) {
        int grow = rowBase + wr + mt * 16 + quad * 4 + r;
        if (grow < Nrows) {
          float v = acc[mt][nt][r];
          if (oc < 128) {
            uint32_t pk = (uint32_t)__builtin_amdgcn_cvt_pk_fp8_f32(v, v, 0, false);
            hq[(size_t)grow * 128 + oc] = (uint8_t)pk;
          } else {
            hr[(size_t)grow * 128 + oc - 128] = (bf16)v;
          }
        }
      }
    }
}

// ---------------- generic GEMM with split epilogue (decoder P|Q) ----------------
template <int KDIM, int EPI>
__global__ __launch_bounds__(256) void k_gemm(
    const bf16* __restrict__ A, const bf16* __restrict__ B,
    const float* __restrict__ bias, void* __restrict__ out1,
    void* __restrict__ out2, int Nrows) {
  __shared__ bf16 As[128 * 64];
  __shared__ bf16 Bs[128 * 64];
  const int tid = threadIdx.x, wave = tid >> 6, lane = tid & 63;
  const int quad = lane >> 4, l16 = lane & 15;
  const int rowBase = blockIdx.y * 128;
  const int colBase = blockIdx.x * 128;
  const int wr = (wave >> 1) * 64;
  const int wc = (wave & 1) * 64;
  floatx4 acc[4][4] = {};

  for (int kc = 0; kc < KDIM / 64; ++kc) {
    for (int i = 0; i < 4; ++i) {
      int u = wave * 256 + i * 64 + lane;
      int row = u >> 3, seg = u & 7;
      int sg = seg ^ (row & 7);
      int node = rowBase + row;
      if (node >= Nrows) node = Nrows - 1;
      async16(A + (size_t)node * KDIM + kc * 64 + sg * 8, &As[(wave * 256 + i * 64) * 8]);
    }
    for (int i = 0; i < 4; ++i) {
      int u = wave * 256 + i * 64 + lane;
      int row = u >> 3, seg = u & 7;
      int sg = seg ^ (row & 7);
      async16(B + (size_t)(colBase + row) * KDIM + kc * 64 + sg * 8,
              &Bs[(wave * 256 + i * 64) * 8]);
    }
    __syncthreads();
    for (int ks = 0; ks < 2; ++ks) {
      bf16x8 af[4], bq[4];
      const int sw = (ks * 4 + quad) ^ (l16 & 7);
      for (int mt = 0; mt < 4; ++mt)
        af[mt] = *(const bf16x8*)&As[(wr + mt * 16 + l16) * 64 + sw * 8];
      for (int nt = 0; nt < 4; ++nt)
        bq[nt] = *(const bf16x8*)&Bs[(wc + nt * 16 + l16) * 64 + sw * 8];
      for (int mt = 0; mt < 4; ++mt)
        for (int nt = 0; nt < 4; ++nt)
          acc[mt][nt] = __builtin_amdgcn_mfma_f32_16x16x32_bf16(af[mt], bq[nt], acc[mt][nt], 0, 0, 0);
    }
    __syncthreads();
  }
  float bv[4];
  for (int nt = 0; nt < 4; ++nt)
    bv[nt] = (EPI == 2) ? bias[colBase + wc + nt * 16 + l16] : 0.0f;
  const bool lowHalf = (colBase == 0);  // 256-col output, tile 0 = cols<128
  for (int mt = 0; mt < 4; ++mt)
    for (int nt = 0; nt < 4; ++nt) {
      int gcol = colBase + wc + nt * 16 + l16;
      for (int r = 0; r < 4; ++r) {
        int grow = rowBase + wr + mt * 16 + quad * 4 + r;
        if (grow < Nrows) {
          float v = acc[mt][nt][r] + bv[nt];
          if (lowHalf) {
            if (EPI == 1) {
              uint32_t pk = (uint32_t)__builtin_amdgcn_cvt_pk_fp8_f32(v, v, 0, false);
              ((uint8_t*)out1)[(size_t)grow * 128 + gcol] = (uint8_t)pk;
            } else {
              ((bf16*)out1)[(size_t)grow * 128 + gcol] = (bf16)v;
            }
          } else {
            ((bf16*)out2)[(size_t)grow * 128 + gcol - 128] = (bf16)v;
          }
        }
      }
    }
}

// ---------------- edge decoder, CSR-ordered ----------------
__global__ __launch_bounds__(256) void k_edge(
    const bf16* __restrict__ P, const bf16* __restrict__ Q,
    const int* __restrict__ rowptr, const int* __restrict__ csr,
    const float* __restrict__ wd2, const float* __restrict__ bd2,
    float* __restrict__ outCSR) {
  int wave = threadIdx.x >> 6, lane = threadIdx.x & 63;
  int n = blockIdx.x * 4 + wave;
  int s = rowptr[n], e = rowptr[n + 1];
  int sub = lane >> 4, l16 = lane & 15;
  bf16x8 qv = *(const bf16x8*)(Q + (size_t)n * 128 + l16 * 8);
  float qf[8];
#pragma unroll
  for (int j = 0; j < 8; ++j) qf[j] = (float)qv[j];
  const float4* w4 = (const float4*)(wd2 + l16 * 8);
  float4 wa = w4[0], wb = w4[1];
  float w[8] = {wa.x, wa.y, wa.z, wa.w, wb.x, wb.y, wb.z, wb.w};
  const float bout = bd2[0];
  int i = s + sub;
  for (; i + 4 < e; i += 8) {
    int c0 = clampN(csr[i]), c1 = clampN(csr[i + 4]);
    bf16x8 p0 = *(const bf16x8*)(P + (size_t)c0 * 128 + l16 * 8);
    bf16x8 p1 = *(const bf16x8*)(P + (size_t)c1 * 128 + l16 * 8);
    float a0 = 0.f, a1 = 0.f;
#pragma unroll
    for (int j = 0; j < 8; ++j) {
      a0 += fmaxf((float)p0[j] + qf[j], 0.f) * w[j];
      a1 += fmaxf((float)p1[j] + qf[j], 0.f) * w[j];
    }
    a0 += __shfl_xor(a0, 1); a1 += __shfl_xor(a1, 1);
    a0 += __shfl_xor(a0, 2); a1 += __shfl_xor(a1, 2);
    a0 += __shfl_xor(a0, 4); a1 += __shfl_xor(a1, 4);
    a0 += __shfl_xor(a0, 8); a1 += __shfl_xor(a1, 8);
    if (l16 == 0) { outCSR[i] = a0 + bout; outCSR[i + 4] = a1 + bout; }
  }
  for (; i < e; i += 4) {
    int c = clampN(csr[i]);
    bf16x8 p = *(const bf16x8*)(P + (size_t)c * 128 + l16 * 8);
    float a = 0.f;
#pragma unroll
    for (int j = 0; j < 8; ++j)
      a += fmaxf((float)p[j] + qf[j], 0.f) * w[j];
    a += __shfl_xor(a, 1);
    a += __shfl_xor(a, 2);
    a += __shfl_xor(a, 4);
    a += __shfl_xor(a, 8);
    if (l16 == 0) outCSR[i] = a + bout;
  }
}

// ---------------- permute CSR-order results to edge order ----------------
__global__ void k_perm(const int* __restrict__ dst, const uint16_t* __restrict__ rank,
                       const int* __restrict__ rptr8, const float* __restrict__ outCSR,
                       float* __restrict__ out, int E) {
  int e = blockIdx.x * 256 + threadIdx.x;
  if (e < E) {
    int d = dst[e];
    uint32_t rv = rank[e];
    int pos = rptr8[(size_t)(rv >> 12) * NN + d] + (int)(rv & 0xFFFu);
    if ((unsigned)pos >= (unsigned)E) pos = 0;  // defensive
    out[e] = outCSR[pos];
  }
}

// ---------------- host ----------------
extern "C" void kernel_launch(void* const* d_in, const int* in_sizes, int n_in,
                              void* d_out, int out_size, void* d_ws, size_t ws_size,
                              hipStream_t stream) {
  const float* x   = (const float*)d_in[0];
  const int*   ei  = (const int*)d_in[1];
  const float* W1l = (const float*)d_in[2];
  const float* b1l = (const float*)d_in[3];
  const float* W1r = (const float*)d_in[4];
  const float* W2l = (const float*)d_in[5];
  const float* b2l = (const float*)d_in[6];
  const float* W2r = (const float*)d_in[7];
  const float* Wd1 = (const float*)d_in[8];
  const float* bd1 = (const float*)d_in[9];
  const float* Wd2 = (const float*)d_in[10];
  const float* bd2 = (const float*)d_in[11];
  float* out = (float*)d_out;

  const int N = NN, E = NE;
  const int* srcv = ei;
  const int* dstv = ei + E;

  char* w = (char*)d_ws;
  size_t off = 0;
  auto take = [&](size_t bytes) {
    size_t o = off;
    off = (off + bytes + 255) & ~(size_t)255;
    return o;
  };
  int*      cnt8   = (int*)(w + take((size_t)8 * N * 4));  // becomes rptr8 in place
  int*      rowptr = (int*)(w + take((size_t)(N + 1) * 4));
  int*      part   = (int*)(w + take((size_t)NB_SCAN * 4));
  uint16_t* rank   = (uint16_t*)(w + take((size_t)E * 2));
  int*      csr    = (int*)(w + take((size_t)E * 4));
  bf16*     xb     = (bf16*)(w + take((size_t)N * 256 * 2));
  uint8_t*  xq     = (uint8_t*)(w + take((size_t)N * 256));
  bf16*     mean   = (bf16*)(w + take((size_t)N * 256 * 2));  // later: P+Q
  bf16*     h      = (bf16*)(w + take((size_t)N * 256 * 2));  // holds hq+hr
  bf16*     zf     = (bf16*)(w + take((size_t)N * 128 * 2));
  bf16*     B1     = (bf16*)(w + take((size_t)131072 * 2));
  bf16*     B2     = (bf16*)(w + take((size_t)65536 * 2));
  bf16*     Bd     = (bf16*)(w + take((size_t)32768 * 2));
  float*    biasPQ = (float*)(w + take((size_t)256 * 4));
  // aliases (producer/consumer ordering makes these safe):
  int*     rptr8 = cnt8;                        // after k_scan_fin's in-place pass
  float*   outCSR = (float*)xb;                 // xb dead after k_fused12
  uint8_t* hq = (uint8_t*)h;                    // [N][128] fp8 (fused kernel out)
  bf16*    hr = (bf16*)(hq + (size_t)N * 128);  // [N][128] bf16
  bf16*    P  = mean;                           // [N][128] bf16 (mean dead after fuse)
  bf16*    Q  = mean + (size_t)N * 128;         // [N][128] bf16
  (void)ws_size; (void)n_in; (void)in_sizes; (void)out_size;

  hipMemsetAsync(cnt8, 0, (size_t)8 * N * 4, stream);

  k_cvtx_hist<<<NB_CVTX + NB_HIST, 256, 0, stream>>>(x, xb, (uint32_t*)xq, dstv, cnt8, rank);
  k_cvtw_scanpart<<<NB_CVTW + NB_SCAN, 256, 0, stream>>>(
      W1l, W1r, W2l, W2r, Wd1, bd1, B1, B2, Bd, biasPQ, cnt8, part, N);
  k_scan_mid<<<1, 512, 0, stream>>>(part, NB_SCAN);
  k_scan_fin<<<NB_SCAN, 256, 0, stream>>>(cnt8, part, rowptr, N, E);
  k_fill<<<E / 256, 256, 0, stream>>>(srcv, dstv, rptr8, rank, csr, E);

  // conv1 aggregation
  k_agg<<<N / 4, 256, 0, stream>>>(xq, rowptr, csr, mean);
  // FUSED: h = relu([mean|x]@B1^T + b1l); [hq|hr] = h @ B2^T  (h stays in LDS)
  k_fused12<<<(NN + 127) / 128, 512, 0, stream>>>(mean, xb, B1, b1l, B2, hq, hr, N);
  // conv2 aggregate+combine: zf = agg_mean(hq) + hr + b2l
  k_agg2z<<<N / 4, 256, 0, stream>>>(hq, hr, rowptr, csr, b2l, zf);
  // decoder node-level: [P|Q] = zf @ Bd^T + [bd1|0]
  k_gemm<128, 2><<<dim3(2, 782), 256, 0, stream>>>(zf, Bd, biasPQ, P, Q, N);
  // decoder edge-level, CSR-ordered
  k_edge<<<N / 4, 256, 0, stream>>>(P, Q, rowptr, csr, Wd2, bd2, outCSR);
  // reorder to edge order
  k_perm<<<E / 256, 256, 0, stream>>>(dstv, rank, rptr8, outCSR, out, E);
}

// Round 7
// 550.681 us; speedup vs baseline: 1.0751x; 1.0751x over previous
//
#include <hip/hip_runtime.h>
#include <stdint.h>

// GNNAutoEncoder: 2x SAGEConv(mean) + edge MLP decoder.
// N=100000 nodes, E=1600000 edges, D=256, HIDDEN=256, OUT=128.
static constexpr int NN = 100000;
static constexpr int NE = 1600000;
static constexpr int NB_SCAN = (NN + 255) / 256;  // 391
static constexpr int NB_CVTX = NN * 256 / 4 / 256;  // 25000
static constexpr int NB_HIST = NE / 256;            // 6250
static constexpr int NB_CVTW = 897;

typedef __bf16 bf16;
typedef __bf16 bf16x4 __attribute__((ext_vector_type(4)));
typedef __bf16 bf16x8 __attribute__((ext_vector_type(8)));
typedef float floatx4 __attribute__((ext_vector_type(4)));

// async global->LDS, 16B per lane. LDS dest is wave-uniform base + lane*16.
__device__ __forceinline__ void async16(const void* g, void* l) {
  __builtin_amdgcn_global_load_lds(
      (const __attribute__((address_space(1))) void*)g,
      (__attribute__((address_space(3))) void*)l, 16, 0, 0);
}

// pack 4 floats -> 4 OCP e4m3 bytes
__device__ __forceinline__ uint32_t pk4_fp8(float a, float b, float c, float d) {
  uint32_t v = 0;
  v = (uint32_t)__builtin_amdgcn_cvt_pk_fp8_f32(a, b, (int)v, false);
  v = (uint32_t)__builtin_amdgcn_cvt_pk_fp8_f32(c, d, (int)v, true);
  return v;
}

// accumulate 8 fp8 (uint2) into float[8]
__device__ __forceinline__ void acc_fp8x8(float* a, uint2 v) {
  a[0] += __builtin_amdgcn_cvt_f32_fp8(v.x, 0);
  a[1] += __builtin_amdgcn_cvt_f32_fp8(v.x, 1);
  a[2] += __builtin_amdgcn_cvt_f32_fp8(v.x, 2);
  a[3] += __builtin_amdgcn_cvt_f32_fp8(v.x, 3);
  a[4] += __builtin_amdgcn_cvt_f32_fp8(v.y, 0);
  a[5] += __builtin_amdgcn_cvt_f32_fp8(v.y, 1);
  a[6] += __builtin_amdgcn_cvt_f32_fp8(v.y, 2);
  a[7] += __builtin_amdgcn_cvt_f32_fp8(v.y, 3);
}

// clamp a gathered index into [0, NN) -- defensive: turns any CSR corruption
// into a wrong answer (diagnosable) instead of a wild-pointer page fault.
__device__ __forceinline__ int clampN(int c) {
  return ((unsigned)c < (unsigned)NN) ? c : 0;
}

// ---------------- fused: x->bf16+fp8 convert | dst histogram + rank ----------------
// XCD-LOCAL histograms: 8 copies of cnt indexed by HW_REG_XCC_ID, updated with
// workgroup-scope atomics executing in the local TCC (XCD-coherent; each XCD
// touches only its own slice). Atomic return = XCD-local rank, (xcd<<12)|rank.
__global__ void k_cvtx_hist(const float* __restrict__ x, bf16* __restrict__ xb,
                            uint32_t* __restrict__ xq,
                            const int* __restrict__ dst, int* __restrict__ cnt8,
                            uint16_t* __restrict__ rank) {
  int b = blockIdx.x;  // 31250 = 5 * 6250 blocks
  int m = b % 5;
  if (m < 4) {
    int cb = (b / 5) * 4 + m;  // 0..24999
    int t = cb * 256 + threadIdx.x;  // 4 elems / thread
    const float4 v = ((const float4*)x)[t];
    bf16x4 o;
    o.x = (bf16)v.x; o.y = (bf16)v.y; o.z = (bf16)v.z; o.w = (bf16)v.w;
    ((bf16x4*)xb)[t] = o;
    xq[t] = pk4_fp8(v.x, v.y, v.z, v.w);
  } else {
    int hb = b / 5;  // 0..6249
    int e = hb * 256 + threadIdx.x;
    uint32_t xcd;
    asm("s_getreg_b32 %0, hwreg(HW_REG_XCC_ID)" : "=s"(xcd));
    xcd &= 7u;
    int d = dst[e];
    int old = __hip_atomic_fetch_add(&cnt8[(size_t)xcd * NN + d], 1,
                                     __ATOMIC_RELAXED, __HIP_MEMORY_SCOPE_WORKGROUP);
    rank[e] = (uint16_t)((xcd << 12) | ((uint32_t)old & 0xFFFu));
  }
}

// ---------------- fused: weight packs | scan partials ----------------
__global__ void k_cvtw_scanpart(
    const float* __restrict__ W1l, const float* __restrict__ W1r,
    const float* __restrict__ W2l, const float* __restrict__ W2r,
    const float* __restrict__ Wd1, const float* __restrict__ bd1,
    bf16* __restrict__ B1, bf16* __restrict__ B2,
    bf16* __restrict__ Bd, float* __restrict__ biasPQ,
    const int* __restrict__ cnt8, int* __restrict__ part, int N) {
  int b = blockIdx.x;
  if (b < NB_CVTW) {
    int g = b * 256 + threadIdx.x;  // 229632 total
    if (g < 131072) {
      int o = g >> 9, k = g & 511;
      float v = (k < 256) ? W1l[o * 256 + k] : W1r[o * 256 + k - 256];
      B1[g] = (bf16)v;
    } else if (g < 131072 + 65536) {
      int t = g - 131072;
      int o = t >> 8, k = t & 255;
      float v = (o < 128) ? W2l[o * 256 + k] : W2r[(o - 128) * 256 + k];
      B2[t] = (bf16)v;
    } else if (g < 131072 + 65536 + 32768) {
      int t = g - 196608;
      int o = t >> 7, k = t & 127;
      float v = (o < 128) ? Wd1[o * 256 + k] : Wd1[(o - 128) * 256 + 128 + k];
      Bd[t] = (bf16)v;
    } else if (g < 131072 + 65536 + 32768 + 256) {
      int t = g - 229376;
      biasPQ[t] = (t < 128) ? bd1[t] : 0.0f;
    }
  } else {
    __shared__ int sh[256];
    int bb = b - NB_CVTW;
    int t = threadIdx.x;
    int i = bb * 256 + t;
    int tot = 0;
    if (i < N) {
#pragma unroll
      for (int xx = 0; xx < 8; ++xx) tot += cnt8[(size_t)xx * NN + i];
    }
    sh[t] = tot;
    __syncthreads();
    for (int off = 128; off > 0; off >>= 1) {
      if (t < off) sh[t] += sh[t + off];
      __syncthreads();
    }
    if (t == 0) part[bb] = sh[0];
  }
}

__global__ __launch_bounds__(512) void k_scan_mid(int* __restrict__ part, int NB) {
  __shared__ int sh[512];
  int t = threadIdx.x;
  int v = (t < NB) ? part[t] : 0;
  sh[t] = v;
  __syncthreads();
  for (int off = 1; off < 512; off <<= 1) {
    int u = (t >= off) ? sh[t - off] : 0;
    __syncthreads();
    sh[t] += u;
    __syncthreads();
  }
  if (t < NB) part[t] = sh[t] - v;  // exclusive
}

// exclusive prefix over per-node totals; converts cnt8 IN PLACE into
// per-(xcd,node) CSR bases: rptr8[x][n] = rowptr[n] + sum_{y<x} cnt8[y][n].
__global__ void k_scan_fin(int* __restrict__ cnt8, const int* __restrict__ part,
                           int* __restrict__ rowptr, int N, int E) {
  __shared__ int sh[256];
  int t = threadIdx.x;
  int i = blockIdx.x * 256 + t;
  int c[8];
  int v = 0;
  if (i < N) {
#pragma unroll
    for (int xx = 0; xx < 8; ++xx) { c[xx] = cnt8[(size_t)xx * NN + i]; v += c[xx]; }
  } else {
#pragma unroll
    for (int xx = 0; xx < 8; ++xx) c[xx] = 0;
  }
  sh[t] = v;
  __syncthreads();
  for (int off = 1; off < 256; off <<= 1) {
    int u = (t >= off) ? sh[t - off] : 0;
    __syncthreads();
    sh[t] += u;
    __syncthreads();
  }
  if (i < N) {
    int base = part[blockIdx.x] + sh[t] - v;  // exclusive prefix
    rowptr[i] = base;
#pragma unroll
    for (int xx = 0; xx < 8; ++xx) { cnt8[(size_t)xx * NN + i] = base; base += c[xx]; }
  }
  if (i == 0) rowptr[N] = E;
}

// atomic-free CSR fill: pos = rptr8[xcd][dst] + local_rank (both from hist).
__global__ void k_fill(const int* __restrict__ src, const int* __restrict__ dst,
                       const int* __restrict__ rptr8,
                       const uint16_t* __restrict__ rank,
                       int* __restrict__ csr, int E) {
  int e = blockIdx.x * 256 + threadIdx.x;
  if (e < E) {
    int d = dst[e];
    uint32_t rv = rank[e];
    int pos = rptr8[(size_t)(rv >> 12) * NN + d] + (int)(rv & 0xFFFu);
    if ((unsigned)pos >= (unsigned)E) pos = 0;  // defensive
    csr[pos] = src[e];
  }
}

// ---------------- layer-1 mean aggregation (fp8 gather, 256 cols) ----------------
__global__ void k_agg(const uint8_t* __restrict__ xq, const int* __restrict__ rowptr,
                      const int* __restrict__ csr, bf16* __restrict__ mean) {
  int wave = threadIdx.x >> 6, lane = threadIdx.x & 63;
  int n = blockIdx.x * 4 + wave;
  int s = rowptr[n], e = rowptr[n + 1];
  int half = lane >> 5, l32 = lane & 31;
  float a[8] = {};
  const uint8_t* base = xq + l32 * 8;
  int i = s + half;
  for (; i + 6 < e; i += 8) {
    int c0 = clampN(csr[i]), c1 = clampN(csr[i + 2]);
    int c2 = clampN(csr[i + 4]), c3 = clampN(csr[i + 6]);
    uint2 v0 = *(const uint2*)(base + (size_t)c0 * 256);
    uint2 v1 = *(const uint2*)(base + (size_t)c1 * 256);
    uint2 v2 = *(const uint2*)(base + (size_t)c2 * 256);
    uint2 v3 = *(const uint2*)(base + (size_t)c3 * 256);
    acc_fp8x8(a, v0); acc_fp8x8(a, v1); acc_fp8x8(a, v2); acc_fp8x8(a, v3);
  }
  for (; i < e; i += 2) {
    uint2 v = *(const uint2*)(base + (size_t)clampN(csr[i]) * 256);
    acc_fp8x8(a, v);
  }
  int deg = e - s;
  float sc = 1.0f / (float)(deg > 0 ? deg : 1);
  bf16x8 o;
#pragma unroll
  for (int j = 0; j < 8; ++j) {
    float t = a[j] + __shfl_xor(a[j], 32);
    o[j] = (bf16)(t * sc);
  }
  if (half == 0)
    *(bf16x8*)(mean + (size_t)n * 256 + l32 * 8) = o;
}

// ---------------- layer-2 aggregate+combine (fp8 hl gather, 128 cols) ----------------
__global__ void k_agg2z(const uint8_t* __restrict__ hq, const bf16* __restrict__ hr,
                        const int* __restrict__ rowptr, const int* __restrict__ csr,
                        const float* __restrict__ b2l, bf16* __restrict__ zf) {
  int wave = threadIdx.x >> 6, lane = threadIdx.x & 63;
  int n = blockIdx.x * 4 + wave;
  int s = rowptr[n], e = rowptr[n + 1];
  int sub = lane >> 4, l16 = lane & 15;
  float a[8] = {};
  const uint8_t* base = hq + l16 * 8;
  int i = s + sub;
  for (; i + 4 < e; i += 8) {
    int c0 = clampN(csr[i]), c1 = clampN(csr[i + 4]);
    uint2 v0 = *(const uint2*)(base + (size_t)c0 * 128);
    uint2 v1 = *(const uint2*)(base + (size_t)c1 * 128);
    acc_fp8x8(a, v0); acc_fp8x8(a, v1);
  }
  for (; i < e; i += 4) {
    uint2 v = *(const uint2*)(base + (size_t)clampN(csr[i]) * 128);
    acc_fp8x8(a, v);
  }
  int deg = e - s;
  float sc = 1.0f / (float)(deg > 0 ? deg : 1);
  bf16x8 hv = *(const bf16x8*)(hr + (size_t)n * 128 + l16 * 8);
  const float4* b4 = (const float4*)(b2l + l16 * 8);
  float4 ba = b4[0], bb = b4[1];
  float bl[8] = {ba.x, ba.y, ba.z, ba.w, bb.x, bb.y, bb.z, bb.w};
  bf16x8 o;
#pragma unroll
  for (int j = 0; j < 8; ++j) {
    float t = a[j];
    t += __shfl_xor(t, 16);
    t += __shfl_xor(t, 32);
    o[j] = (bf16)(t * sc + (float)hv[j] + bl[j]);
  }
  if (sub == 0)
    *(bf16x8*)(zf + (size_t)n * 128 + l16 * 8) = o;
}

// ---------------- FUSED conv1 GEMM + conv2 transform (128-row, dbuf+counted vmcnt) ----
// Phase 1 (steps 0..7):  h = relu([mean|x] @ B1^T + b1l), acc in regs -> Hs (LDS).
// Phase 2 (steps 8..11): [hq|hr] = h @ B2^T, A read from Hs; h never touches HBM.
// Pipelined: stage(s+1) issued BEFORE computing step s, waits are counted
// (vmcnt(6)/vmcnt(4)), never 0 in the steady state.
// r6 regression root-caused: compiler capped VGPR at 128 (default 4-waves/SIMD
// occupancy target) and spilled ~8B/thread/iter (WRITE_SIZE 37.5->75MB).
// Fixes here: __launch_bounds__(512,2) -> 256-VGPR budget (LDS caps us at
// 2 waves/SIMD anyway), fully-unrolled split loops with statically-named
// buffers (no runtime parity indexing), and lgkmcnt(0) before the barrier
// after the Hs epilogue (raw s_barrier does not drain LDS writes).
// LDS = Hs 64KB + 2xAs 32KB + 2xBs 64KB = 160KB (1 block/CU).
__global__ __launch_bounds__(512, 2) void k_fused12(
    const bf16* __restrict__ A1, const bf16* __restrict__ A2,
    const bf16* __restrict__ B1, const float* __restrict__ b1l,
    const bf16* __restrict__ B2, uint8_t* __restrict__ hq,
    bf16* __restrict__ hr, int Nrows) {
  __shared__ bf16 Hs[128 * 256];  // 64KB; chunk c of row stored at c^(row&7)
  __shared__ bf16 As0[128 * 64], As1[128 * 64];  // 2 x 16KB
  __shared__ bf16 Bs0[256 * 64], Bs1[256 * 64];  // 2 x 32KB
  const int tid = threadIdx.x, wave = tid >> 6, lane = tid & 63;
  const int quad = lane >> 4, l16 = lane & 15;
  const int rowBase = blockIdx.x * 128;
  const int wr = (wave >> 2) * 64;  // 0,64
  const int wc = (wave & 3) * 64;   // 0,64,128,192
  floatx4 acc[4][4] = {};

  auto stageA = [&](int kc, bf16* dst) {  // 2 vmem insts / wave
    const bf16* Asrc = (kc < 4) ? A1 : A2;
    const int kb = (kc & 3) * 64;
#pragma unroll
    for (int i = 0; i < 2; ++i) {
      int u = wave * 128 + i * 64 + lane;
      int row = u >> 3, seg = u & 7;
      int sg = seg ^ (row & 7);
      int node = rowBase + row;
      if (node >= Nrows) node = Nrows - 1;
      async16(Asrc + (size_t)node * 256 + kb + sg * 8, dst + (wave * 128 + i * 64) * 8);
    }
  };
  auto stageB1 = [&](int kc, bf16* dst) {  // 4 vmem insts / wave
#pragma unroll
    for (int i = 0; i < 4; ++i) {
      int u = wave * 256 + i * 64 + lane;
      int row = u >> 3, seg = u & 7;
      int sg = seg ^ (row & 7);
      async16(B1 + (size_t)row * 512 + kc * 64 + sg * 8, dst + (wave * 256 + i * 64) * 8);
    }
  };
  auto stageB2 = [&](int kc, bf16* dst) {  // 4 vmem insts / wave
#pragma unroll
    for (int i = 0; i < 4; ++i) {
      int u = wave * 256 + i * 64 + lane;
      int row = u >> 3, seg = u & 7;
      int sg = seg ^ (row & 7);
      async16(B2 + (size_t)row * 256 + kc * 64 + sg * 8, dst + (wave * 256 + i * 64) * 8);
    }
  };
  auto compute1 = [&](const bf16* asb, const bf16* bsb) {
#pragma unroll
    for (int ks = 0; ks < 2; ++ks) {
      bf16x8 af[4], bq[4];
      const int sw = (ks * 4 + quad) ^ (l16 & 7);
#pragma unroll
      for (int mt = 0; mt < 4; ++mt)
        af[mt] = *(const bf16x8*)&asb[(wr + mt * 16 + l16) * 64 + sw * 8];
#pragma unroll
      for (int nt = 0; nt < 4; ++nt)
        bq[nt] = *(const bf16x8*)&bsb[(wc + nt * 16 + l16) * 64 + sw * 8];
#pragma unroll
      for (int mt = 0; mt < 4; ++mt)
#pragma unroll
        for (int nt = 0; nt < 4; ++nt)
          acc[mt][nt] = __builtin_amdgcn_mfma_f32_16x16x32_bf16(af[mt], bq[nt], acc[mt][nt], 0, 0, 0);
    }
  };
  auto compute2 = [&](int kc, const bf16* bsb) {
#pragma unroll
    for (int ks = 0; ks < 2; ++ks) {
      bf16x8 af[4], bq[4];
      const int swb = (ks * 4 + quad) ^ (l16 & 7);
      const int ck = kc * 8 + ks * 4 + quad;  // global h chunk 0..31
#pragma unroll
      for (int mt = 0; mt < 4; ++mt) {
        int row = wr + mt * 16 + l16;
        af[mt] = *(const bf16x8*)&Hs[row * 256 + (ck ^ (row & 7)) * 8];
      }
#pragma unroll
      for (int nt = 0; nt < 4; ++nt)
        bq[nt] = *(const bf16x8*)&bsb[(wc + nt * 16 + l16) * 64 + swb * 8];
#pragma unroll
      for (int mt = 0; mt < 4; ++mt)
#pragma unroll
        for (int nt = 0; nt < 4; ++nt)
          acc[mt][nt] = __builtin_amdgcn_mfma_f32_16x16x32_bf16(af[mt], bq[nt], acc[mt][nt], 0, 0, 0);
    }
  };

  // prologue: stage step 0 into buf0
  stageA(0, As0);
  stageB1(0, Bs0);

  // ---- phase 1: 8 steps, unrolled in pairs (even->buf0, odd->buf1) ----
#pragma unroll
  for (int sp = 0; sp < 4; ++sp) {
    const int s1 = sp * 2 + 1;
    // even step 2sp computes buf0; first stage step s1 into buf1
    stageA(s1, As1);
    stageB1(s1, Bs1);
    asm volatile("s_waitcnt vmcnt(6)" ::: "memory");  // step-2sp loads landed
    __builtin_amdgcn_sched_barrier(0);
    __builtin_amdgcn_s_barrier();
    compute1(As0, Bs0);
    __builtin_amdgcn_s_barrier();
    // odd step s1 computes buf1; stage next into buf0
    if (s1 < 7) {
      stageA(s1 + 1, As0);
      stageB1(s1 + 1, Bs0);
      asm volatile("s_waitcnt vmcnt(6)" ::: "memory");
    } else {
      stageB2(0, Bs0);  // first phase-2 tile
      asm volatile("s_waitcnt vmcnt(4)" ::: "memory");
    }
    __builtin_amdgcn_sched_barrier(0);
    __builtin_amdgcn_s_barrier();
    compute1(As1, Bs1);
    if (s1 == 7) {
      // epilogue 1: bias + relu -> Hs; zero acc for phase 2
      float bv1[4];
#pragma unroll
      for (int nt = 0; nt < 4; ++nt) bv1[nt] = b1l[wc + nt * 16 + l16];
#pragma unroll
      for (int mt = 0; mt < 4; ++mt)
#pragma unroll
        for (int nt = 0; nt < 4; ++nt) {
          int col = wc + nt * 16 + l16;
          int c = col >> 3;
#pragma unroll
          for (int r = 0; r < 4; ++r) {
            int row = wr + mt * 16 + quad * 4 + r;
            float v = fmaxf(acc[mt][nt][r] + bv1[nt], 0.0f);
            Hs[row * 256 + (c ^ (row & 7)) * 8 + (col & 7)] = (bf16)v;
            acc[mt][nt][r] = 0.0f;
          }
        }
      asm volatile("s_waitcnt lgkmcnt(0)" ::: "memory");  // Hs writes committed
    }
    __builtin_amdgcn_s_barrier();
  }

  // ---- phase 2: 4 steps, unrolled in pairs (even->Bs0, odd->Bs1) ----
#pragma unroll
  for (int tp = 0; tp < 2; ++tp) {
    const int t1 = tp * 2 + 1;  // 1, 3
    stageB2(t1, Bs1);
    asm volatile("s_waitcnt vmcnt(4)" ::: "memory");
    __builtin_amdgcn_sched_barrier(0);
    __builtin_amdgcn_s_barrier();
    compute2(tp * 2, Bs0);
    __builtin_amdgcn_s_barrier();
    if (t1 < 3) {
      stageB2(t1 + 1, Bs0);
      asm volatile("s_waitcnt vmcnt(4)" ::: "memory");
    } else {
      asm volatile("s_waitcnt vmcnt(0)" ::: "memory");
    }
    __builtin_amdgcn_sched_barrier(0);
    __builtin_amdgcn_s_barrier();
    compute2(t1, Bs1);
    __builtin_amdgcn_s_barrier();
  }

  // ---- epilogue 2: oc<128 -> hq fp8, oc>=128 -> hr bf16 (no bias) ----
#pragma unroll
  for (int mt = 0; mt < 4; ++mt)
#pragma unroll
    for (int nt = 0; nt < 4; ++nt) {
      int oc = wc + nt * 16 + l16;
#pragma unroll
      for (int r = 0; r < 4; ++r) {
        int grow = rowBase + wr + mt * 16 + quad * 4 + r;
        if (grow < Nrows) {
          float v = acc[mt][nt][r];
          if (oc < 128) {
            uint32_t pk = (uint32_t)__builtin_amdgcn_cvt_pk_fp8_f32(v, v, 0, false);
            hq[(size_t)grow * 128 + oc] = (uint8_t)pk;
          } else {
            hr[(size_t)grow * 128 + oc - 128] = (bf16)v;
          }
        }
      }
    }
}

// ---------------- generic GEMM with split epilogue (decoder P|Q) ----------------
template <int KDIM, int EPI>
__global__ __launch_bounds__(256) void k_gemm(
    const bf16* __restrict__ A, const bf16* __restrict__ B,
    const float* __restrict__ bias, void* __restrict__ out1,
    void* __restrict__ out2, int Nrows) {
  __shared__ bf16 As[128 * 64];
  __shared__ bf16 Bs[128 * 64];
  const int tid = threadIdx.x, wave = tid >> 6, lane = tid & 63;
  const int quad = lane >> 4, l16 = lane & 15;
  const int rowBase = blockIdx.y * 128;
  const int colBase = blockIdx.x * 128;
  const int wr = (wave >> 1) * 64;
  const int wc = (wave & 1) * 64;
  floatx4 acc[4][4] = {};

  for (int kc = 0; kc < KDIM / 64; ++kc) {
    for (int i = 0; i < 4; ++i) {
      int u = wave * 256 + i * 64 + lane;
      int row = u >> 3, seg = u & 7;
      int sg = seg ^ (row & 7);
      int node = rowBase + row;
      if (node >= Nrows) node = Nrows - 1;
      async16(A + (size_t)node * KDIM + kc * 64 + sg * 8, &As[(wave * 256 + i * 64) * 8]);
    }
    for (int i = 0; i < 4; ++i) {
      int u = wave * 256 + i * 64 + lane;
      int row = u >> 3, seg = u & 7;
      int sg = seg ^ (row & 7);
      async16(B + (size_t)(colBase + row) * KDIM + kc * 64 + sg * 8,
              &Bs[(wave * 256 + i * 64) * 8]);
    }
    __syncthreads();
    for (int ks = 0; ks < 2; ++ks) {
      bf16x8 af[4], bq[4];
      const int sw = (ks * 4 + quad) ^ (l16 & 7);
      for (int mt = 0; mt < 4; ++mt)
        af[mt] = *(const bf16x8*)&As[(wr + mt * 16 + l16) * 64 + sw * 8];
      for (int nt = 0; nt < 4; ++nt)
        bq[nt] = *(const bf16x8*)&Bs[(wc + nt * 16 + l16) * 64 + sw * 8];
      for (int mt = 0; mt < 4; ++mt)
        for (int nt = 0; nt < 4; ++nt)
          acc[mt][nt] = __builtin_amdgcn_mfma_f32_16x16x32_bf16(af[mt], bq[nt], acc[mt][nt], 0, 0, 0);
    }
    __syncthreads();
  }
  float bv[4];
  for (int nt = 0; nt < 4; ++nt)
    bv[nt] = (EPI == 2) ? bias[colBase + wc + nt * 16 + l16] : 0.0f;
  const bool lowHalf = (colBase == 0);  // 256-col output, tile 0 = cols<128
  for (int mt = 0; mt < 4; ++mt)
    for (int nt = 0; nt < 4; ++nt) {
      int gcol = colBase + wc + nt * 16 + l16;
      for (int r = 0; r < 4; ++r) {
        int grow = rowBase + wr + mt * 16 + quad * 4 + r;
        if (grow < Nrows) {
          float v = acc[mt][nt][r] + bv[nt];
          if (lowHalf) {
            if (EPI == 1) {
              uint32_t pk = (uint32_t)__builtin_amdgcn_cvt_pk_fp8_f32(v, v, 0, false);
              ((uint8_t*)out1)[(size_t)grow * 128 + gcol] = (uint8_t)pk;
            } else {
              ((bf16*)out1)[(size_t)grow * 128 + gcol] = (bf16)v;
            }
          } else {
            ((bf16*)out2)[(size_t)grow * 128 + gcol - 128] = (bf16)v;
          }
        }
      }
    }
}

// ---------------- edge decoder, CSR-ordered ----------------
__global__ __launch_bounds__(256) void k_edge(
    const bf16* __restrict__ P, const bf16* __restrict__ Q,
    const int* __restrict__ rowptr, const int* __restrict__ csr,
    const float* __restrict__ wd2, const float* __restrict__ bd2,
    float* __restrict__ outCSR) {
  int wave = threadIdx.x >> 6, lane = threadIdx.x & 63;
  int n = blockIdx.x * 4 + wave;
  int s = rowptr[n], e = rowptr[n + 1];
  int sub = lane >> 4, l16 = lane & 15;
  bf16x8 qv = *(const bf16x8*)(Q + (size_t)n * 128 + l16 * 8);
  float qf[8];
#pragma unroll
  for (int j = 0; j < 8; ++j) qf[j] = (float)qv[j];
  const float4* w4 = (const float4*)(wd2 + l16 * 8);
  float4 wa = w4[0], wb = w4[1];
  float w[8] = {wa.x, wa.y, wa.z, wa.w, wb.x, wb.y, wb.z, wb.w};
  const float bout = bd2[0];
  int i = s + sub;
  for (; i + 4 < e; i += 8) {
    int c0 = clampN(csr[i]), c1 = clampN(csr[i + 4]);
    bf16x8 p0 = *(const bf16x8*)(P + (size_t)c0 * 128 + l16 * 8);
    bf16x8 p1 = *(const bf16x8*)(P + (size_t)c1 * 128 + l16 * 8);
    float a0 = 0.f, a1 = 0.f;
#pragma unroll
    for (int j = 0; j < 8; ++j) {
      a0 += fmaxf((float)p0[j] + qf[j], 0.f) * w[j];
      a1 += fmaxf((float)p1[j] + qf[j], 0.f) * w[j];
    }
    a0 += __shfl_xor(a0, 1); a1 += __shfl_xor(a1, 1);
    a0 += __shfl_xor(a0, 2); a1 += __shfl_xor(a1, 2);
    a0 += __shfl_xor(a0, 4); a1 += __shfl_xor(a1, 4);
    a0 += __shfl_xor(a0, 8); a1 += __shfl_xor(a1, 8);
    if (l16 == 0) { outCSR[i] = a0 + bout; outCSR[i + 4] = a1 + bout; }
  }
  for (; i < e; i += 4) {
    int c = clampN(csr[i]);
    bf16x8 p = *(const bf16x8*)(P + (size_t)c * 128 + l16 * 8);
    float a = 0.f;
#pragma unroll
    for (int j = 0; j < 8; ++j)
      a += fmaxf((float)p[j] + qf[j], 0.f) * w[j];
    a += __shfl_xor(a, 1);
    a += __shfl_xor(a, 2);
    a += __shfl_xor(a, 4);
    a += __shfl_xor(a, 8);
    if (l16 == 0) outCSR[i] = a + bout;
  }
}

// ---------------- permute CSR-order results to edge order ----------------
__global__ void k_perm(const int* __restrict__ dst, const uint16_t* __restrict__ rank,
                       const int* __restrict__ rptr8, const float* __restrict__ outCSR,
                       float* __restrict__ out, int E) {
  int e = blockIdx.x * 256 + threadIdx.x;
  if (e < E) {
    int d = dst[e];
    uint32_t rv = rank[e];
    int pos = rptr8[(size_t)(rv >> 12) * NN + d] + (int)(rv & 0xFFFu);
    if ((unsigned)pos >= (unsigned)E) pos = 0;  // defensive
    out[e] = outCSR[pos];
  }
}

// ---------------- host ----------------
extern "C" void kernel_launch(void* const* d_in, const int* in_sizes, int n_in,
                              void* d_out, int out_size, void* d_ws, size_t ws_size,
                              hipStream_t stream) {
  const float* x   = (const float*)d_in[0];
  const int*   ei  = (const int*)d_in[1];
  const float* W1l = (const float*)d_in[2];
  const float* b1l = (const float*)d_in[3];
  const float* W1r = (const float*)d_in[4];
  const float* W2l = (const float*)d_in[5];
  const float* b2l = (const float*)d_in[6];
  const float* W2r = (const float*)d_in[7];
  const float* Wd1 = (const float*)d_in[8];
  const float* bd1 = (const float*)d_in[9];
  const float* Wd2 = (const float*)d_in[10];
  const float* bd2 = (const float*)d_in[11];
  float* out = (float*)d_out;

  const int N = NN, E = NE;
  const int* srcv = ei;
  const int* dstv = ei + E;

  char* w = (char*)d_ws;
  size_t off = 0;
  auto take = [&](size_t bytes) {
    size_t o = off;
    off = (off + bytes + 255) & ~(size_t)255;
    return o;
  };
  int*      cnt8   = (int*)(w + take((size_t)8 * N * 4));  // becomes rptr8 in place
  int*      rowptr = (int*)(w + take((size_t)(N + 1) * 4));
  int*      part   = (int*)(w + take((size_t)NB_SCAN * 4));
  uint16_t* rank   = (uint16_t*)(w + take((size_t)E * 2));
  int*      csr    = (int*)(w + take((size_t)E * 4));
  bf16*     xb     = (bf16*)(w + take((size_t)N * 256 * 2));
  uint8_t*  xq     = (uint8_t*)(w + take((size_t)N * 256));
  bf16*     mean   = (bf16*)(w + take((size_t)N * 256 * 2));  // later: P+Q
  bf16*     h      = (bf16*)(w + take((size_t)N * 256 * 2));  // holds hq+hr
  bf16*     zf     = (bf16*)(w + take((size_t)N * 128 * 2));
  bf16*     B1     = (bf16*)(w + take((size_t)131072 * 2));
  bf16*     B2     = (bf16*)(w + take((size_t)65536 * 2));
  bf16*     Bd     = (bf16*)(w + take((size_t)32768 * 2));
  float*    biasPQ = (float*)(w + take((size_t)256 * 4));
  // aliases (producer/consumer ordering makes these safe):
  int*     rptr8 = cnt8;                        // after k_scan_fin's in-place pass
  float*   outCSR = (float*)xb;                 // xb dead after k_fused12
  uint8_t* hq = (uint8_t*)h;                    // [N][128] fp8 (fused kernel out)
  bf16*    hr = (bf16*)(hq + (size_t)N * 128);  // [N][128] bf16
  bf16*    P  = mean;                           // [N][128] bf16 (mean dead after fuse)
  bf16*    Q  = mean + (size_t)N * 128;         // [N][128] bf16
  (void)ws_size; (void)n_in; (void)in_sizes; (void)out_size;

  hipMemsetAsync(cnt8, 0, (size_t)8 * N * 4, stream);

  k_cvtx_hist<<<NB_CVTX + NB_HIST, 256, 0, stream>>>(x, xb, (uint32_t*)xq, dstv, cnt8, rank);
  k_cvtw_scanpart<<<NB_CVTW + NB_SCAN, 256, 0, stream>>>(
      W1l, W1r, W2l, W2r, Wd1, bd1, B1, B2, Bd, biasPQ, cnt8, part, N);
  k_scan_mid<<<1, 512, 0, stream>>>(part, NB_SCAN);
  k_scan_fin<<<NB_SCAN, 256, 0, stream>>>(cnt8, part, rowptr, N, E);
  k_fill<<<E / 256, 256, 0, stream>>>(srcv, dstv, rptr8, rank, csr, E);

  // conv1 aggregation
  k_agg<<<N / 4, 256, 0, stream>>>(xq, rowptr, csr, mean);
  // FUSED: h = relu([mean|x]@B1^T + b1l); [hq|hr] = h @ B2^T  (h stays in LDS)
  k_fused12<<<(NN + 127) / 128, 512, 0, stream>>>(mean, xb, B1, b1l, B2, hq, hr, N);
  // conv2 aggregate+combine: zf = agg_mean(hq) + hr + b2l
  k_agg2z<<<N / 4, 256, 0, stream>>>(hq, hr, rowptr, csr, b2l, zf);
  // decoder node-level: [P|Q] = zf @ Bd^T + [bd1|0]
  k_gemm<128, 2><<<dim3(2, 782), 256, 0, stream>>>(zf, Bd, biasPQ, P, Q, N);
  // decoder edge-level, CSR-ordered
  k_edge<<<N / 4, 256, 0, stream>>>(P, Q, rowptr, csr, Wd2, bd2, outCSR);
  // reorder to edge order
  k_perm<<<E / 256, 256, 0, stream>>>(dstv, rank, rptr8, outCSR, out, E);
}